// Round 1
// baseline (11053.982 us; speedup 1.0000x reference)
//
#include <hip/hip_runtime.h>
#include <math.h>

// Problem constants (fixed by setup_inputs)
#define NN   256   // nodes
#define HH   450   // hidden
#define LATD 56    // latent
#define VV   780   // vocab
#define LL   511   // path length (2N-1)
#define GSEQ 32    // persistent blocks
#define TSEQ 512   // threads per persistent block

__device__ __forceinline__ float wred_sum(float v) {
    for (int off = 32; off; off >>= 1) v += __shfl_down(v, off, 64);
    return v;
}

// ---- device-scope slot/flag grid barrier (monotonic phase counter) ----
__device__ __forceinline__ void gridbar(unsigned* slots, unsigned ph) {
    __syncthreads();
    const int tid = threadIdx.x, bid = blockIdx.x;
    if (tid == 0) {
        __threadfence();  // publish this block's writes device-wide
        __hip_atomic_store(&slots[bid], ph, __ATOMIC_RELEASE, __HIP_MEMORY_SCOPE_AGENT);
    }
    if (bid == 0) {
        if (tid < GSEQ) {
            while (__hip_atomic_load(&slots[tid], __ATOMIC_ACQUIRE, __HIP_MEMORY_SCOPE_AGENT) < ph) {
                __builtin_amdgcn_s_sleep(1);
            }
        }
        __syncthreads();
        if (tid == 0)
            __hip_atomic_store(&slots[GSEQ], ph, __ATOMIC_RELEASE, __HIP_MEMORY_SCOPE_AGENT);
    } else {
        if (tid == 0) {
            while (__hip_atomic_load(&slots[GSEQ], __ATOMIC_ACQUIRE, __HIP_MEMORY_SCOPE_AGENT) < ph) {
                __builtin_amdgcn_s_sleep(1);
            }
            __threadfence();
        }
    }
    __syncthreads();
}

// ---- find vocab id of each node's one-hot feature ----
__global__ void k_vid(const float* __restrict__ nf, int* __restrict__ vid) {
    const int u = blockIdx.x;
    for (int v = threadIdx.x; v < VV; v += blockDim.x)
        if (nf[(size_t)u * VV + v] > 0.5f) vid[u] = v;
}

// ---- per-node constants: cz, r1, sigma(r1), ch, and Ud . relu(d12) scalar ----
__global__ __launch_bounds__(512) void k_consts(
    const int* __restrict__ vid, const float* __restrict__ latent,
    const float* __restrict__ Wz, const float* __restrict__ Wzb,
    const float* __restrict__ Wr, const float* __restrict__ Wrb,
    const float* __restrict__ Wh, const float* __restrict__ Whb,
    const float* __restrict__ Wd12, const float* __restrict__ Wd12b,
    const float* __restrict__ Ud,
    float* __restrict__ cz, float* __restrict__ r1s, float* __restrict__ sig0,
    float* __restrict__ ch, float* __restrict__ dotd12)
{
    const int u = blockIdx.x, tid = threadIdx.x;
    const int v = vid[u];
    __shared__ float red[8];
    float p = 0.f;
    if (tid < HH) {
        const int i = tid, o = u * HH + i;
        cz[o] = Wz[(size_t)i * (VV + HH) + v] + Wzb[i];
        const float r1 = Wr[(size_t)i * VV + v] + Wrb[i];
        r1s[o] = r1;
        sig0[o] = 1.f / (1.f + expf(-r1));
        ch[o] = Wh[(size_t)i * (VV + HH) + v] + Whb[i];
        float d = Wd12[(size_t)i * (VV + LATD) + v] + Wd12b[i];
        for (int k = 0; k < LATD; ++k)
            d += Wd12[(size_t)i * (VV + LATD) + VV + k] * latent[k];
        p = Ud[i] * fmaxf(d, 0.f);
    }
    p = wred_sum(p);
    if ((tid & 63) == 0) red[tid >> 6] = p;
    __syncthreads();
    if (tid == 0) {
        float s = 0.f;
        for (int w = 0; w < 8; ++w) s += red[w];
        dotd12[u] = s;
    }
}

// ---- WhSig0[u] = Wh_H @ sigma(r1[u]) ----
__global__ __launch_bounds__(512) void k_whsig0(
    const float* __restrict__ Wh, const float* __restrict__ sig0, float* __restrict__ out)
{
    const int u = blockIdx.x, tid = threadIdx.x, wave = tid >> 6, lane = tid & 63;
    __shared__ float sg[HH];
    if (tid < HH) sg[tid] = sig0[u * HH + tid];
    __syncthreads();
    for (int r = wave; r < HH; r += 8) {
        float acc = 0.f;
        for (int k = lane; k < HH; k += 64)
            acc += Wh[(size_t)r * (VV + HH) + VV + k] * sg[k];
        acc = wred_sum(acc);
        if (lane == 0) out[u * HH + r] = acc;
    }
}

// ---- per-step exclusion index: step t' < t that created message b_t -> a_t ----
__global__ void k_excl(const int* __restrict__ node_ids, const int* __restrict__ next_ids,
                       int* __restrict__ excl)
{
    const int t = blockIdx.x;
    if (threadIdx.x == 0) excl[t] = -1;
    __syncthreads();
    const int a = node_ids[t], b = next_ids[t];
    for (int tp = threadIdx.x; tp < t; tp += blockDim.x)
        if (node_ids[tp] == b && next_ids[tp] == a) excl[t] = tp;
}

// ---- copy stops and real_labels into d_out as float ----
__global__ void k_copy(const int* __restrict__ stops, const int* __restrict__ reall,
                       float* __restrict__ out)
{
    const int i = blockIdx.x * blockDim.x + threadIdx.x;
    if (i < LL) out[i] = (float)stops[i];
    if (i < NN) out[2 * LL + i] = (float)reall[i];
}

// ---- the sequential scan: persistent kernel, 2 grid barriers per step ----
__global__ __launch_bounds__(TSEQ) void k_seq(
    const int* __restrict__ node_ids, const int* __restrict__ excl,
    const float* __restrict__ Ur, const float* __restrict__ Wz,
    const float* __restrict__ Wh, const float* __restrict__ Wd3,
    const float* __restrict__ Wd3b, const float* __restrict__ Ud,
    const float* __restrict__ Udb,
    const float* __restrict__ cz, const float* __restrict__ r1s,
    const float* __restrict__ ch, const float* __restrict__ WhSig0,
    const float* __restrict__ dotd12,
    float* __restrict__ Sm, float* __restrict__ WzSm,
    float* __restrict__ Wd3Sm, float* __restrict__ WhRs,
    int* __restrict__ Cnt,
    float* __restrict__ NewH, float* __restrict__ WzM,
    float* __restrict__ WhSv, float* __restrict__ UrM,
    float* __restrict__ pred_out, unsigned* __restrict__ bar)
{
    const int tid = threadIdx.x, bid = blockIdx.x;
    const int wave = tid >> 6, lane = tid & 63;
    const int gw = bid * (TSEQ / 64) + wave;      // global wave id, 0..255
    __shared__ float nh_s[HH];
    __shared__ float psred[TSEQ / 64];
    unsigned ph = 0;

    for (int t = 1; t <= LL; ++t) {
        const int ap  = node_ids[t - 1];
        const int idx = excl[t - 1];
        // ---- P3(t-1): redundantly compute new_h(t-1) in every block ----
        if (tid < HH) {
            const int o = ap * HH + tid;
            float zarg = WzSm[o] + cz[o];
            float whv  = WhRs[o] + ch[o];
            float sv   = Sm[o];
            float e = 0.f;
            if (idx >= 0) {
                const int oe = idx * HH + tid;
                zarg -= WzM[oe]; whv -= WhSv[oe]; sv -= NewH[oe];
                e = 1.f;
            }
            const float cc = 256.f - (float)Cnt[ap] + e;
            whv += cc * WhSig0[o];
            const float z = 1.f / (1.f + expf(-zarg));
            const float g = tanhf(whv);
            nh_s[tid] = (1.f - z) * sv + z * g;
        }
        // pred_stop(t-1): block 0 reduces Ud[H:] . relu(Wd3Sm[ap] + b3)
        float ps = 0.f;
        if (bid == 0 && tid < HH)
            ps = Ud[HH + tid] * fmaxf(Wd3Sm[ap * HH + tid] + Wd3b[tid], 0.f);
        ps = wred_sum(ps);
        if (lane == 0) psred[wave] = ps;
        __syncthreads();
        if (bid == 0) {
            if (tid < HH) NewH[(size_t)(t - 1) * HH + tid] = nh_s[tid];
            if (tid == 0) {
                float s = 0.f;
                for (int w = 0; w < TSEQ / 64; ++w) s += psred[w];
                pred_out[t - 1] = s + dotd12[ap] + Udb[0];
            }
        }
        if (t == LL) break;   // tail: last new_h/pred_stop written, no further message

        const int a = node_ids[t];
        if (bid == 1 && tid < HH) Sm[a * HH + tid] += nh_s[tid];
        // ---- P1(t): ingest message m = new_h(t-1) into node a: Ur@m, Wz_H@m, Wd3@m ----
        for (int r = gw; r < 3 * HH; r += GSEQ * (TSEQ / 64)) {
            const float* wrow; int i, kind;
            if (r < HH)          { kind = 0; i = r;          wrow = Ur  + (size_t)i * HH; }
            else if (r < 2 * HH) { kind = 1; i = r - HH;     wrow = Wz  + (size_t)i * (VV + HH) + VV; }
            else                 { kind = 2; i = r - 2 * HH; wrow = Wd3 + (size_t)i * HH; }
            float acc = 0.f;
            for (int k = lane; k < HH; k += 64) acc += wrow[k] * nh_s[k];
            acc = wred_sum(acc);
            if (lane == 0) {
                if (kind == 0)      UrM[i] = acc;
                else if (kind == 1) { WzM[(size_t)(t - 1) * HH + i] = acc; WzSm[a * HH + i] += acc; }
                else                Wd3Sm[a * HH + i] += acc;
            }
        }
        gridbar(bar, ++ph);
        // ---- P2(t): WhS = Wh_H @ sigma(r1[a] + UrM)  (sigma folded into the dot) ----
        for (int r = gw; r < HH; r += GSEQ * (TSEQ / 64)) {
            float acc = 0.f;
            for (int k = lane; k < HH; k += 64) {
                const float u  = UrM[k] + r1s[a * HH + k];
                const float sg = 1.f / (1.f + expf(-u));
                acc += Wh[(size_t)r * (VV + HH) + VV + k] * sg;
            }
            acc = wred_sum(acc);
            if (lane == 0) { WhSv[(size_t)(t - 1) * HH + r] = acc; WhRs[a * HH + r] += acc; }
        }
        if (bid == 0 && tid == 0) Cnt[a] += 1;
        gridbar(bar, ++ph);
    }
}

// ---- labels: root (q=0, outer relu, no softmax) + 255 label steps (softmax) ----
__global__ __launch_bounds__(512) void k_label(
    const float* __restrict__ latent, const int* __restrict__ lsteps,
    const float* __restrict__ NewH,
    const float* __restrict__ Wl, const float* __restrict__ Wlb,
    const float* __restrict__ Ul, const float* __restrict__ Ulb,
    float* __restrict__ out)
{
    const int q = blockIdx.x, tid = threadIdx.x, wave = tid >> 6, lane = tid & 63;
    __shared__ float inp[LATD + HH];
    __shared__ float t2[HH];
    __shared__ float lg[VV];
    __shared__ float red[8];
    if (tid < LATD) inp[tid] = latent[tid];
    if (q == 0) {
        if (tid < HH) inp[LATD + tid] = 0.f;
    } else {
        const int t = lsteps[q - 1];
        if (tid < HH) inp[LATD + tid] = NewH[(size_t)t * HH + tid];
    }
    __syncthreads();
    for (int r = wave; r < HH; r += 8) {
        float acc = 0.f;
        for (int k = lane; k < LATD + HH; k += 64)
            acc += Wl[(size_t)r * (LATD + HH) + k] * inp[k];
        acc = wred_sum(acc);
        if (lane == 0) {
            const float v = acc + Wlb[r];
            t2[r] = (q == 0) ? v : fmaxf(v, 0.f);   // root: no inner relu
        }
    }
    __syncthreads();
    for (int r = wave; r < VV; r += 8) {
        float acc = 0.f;
        for (int k = lane; k < HH; k += 64) acc += Ul[(size_t)r * HH + k] * t2[k];
        acc = wred_sum(acc);
        if (lane == 0) lg[r] = acc + Ulb[r];
    }
    __syncthreads();
    float* outrow = out + 2 * LL + NN + (size_t)q * VV;
    if (q == 0) {   // root: relu, no softmax
        for (int i = tid; i < VV; i += 512) outrow[i] = fmaxf(lg[i], 0.f);
        return;
    }
    float mx = -1e30f;
    for (int i = tid; i < VV; i += 512) mx = fmaxf(mx, lg[i]);
    for (int off = 32; off; off >>= 1) mx = fmaxf(mx, __shfl_down(mx, off, 64));
    if (lane == 0) red[wave] = mx;
    __syncthreads();
    if (tid == 0) {
        float m = red[0];
        for (int w = 1; w < 8; ++w) m = fmaxf(m, red[w]);
        red[0] = m;
    }
    __syncthreads();
    const float M = red[0];
    float sum = 0.f;
    for (int i = tid; i < VV; i += 512) { const float e = expf(lg[i] - M); lg[i] = e; sum += e; }
    __syncthreads();   // everyone has read M; red reusable
    sum = wred_sum(sum);
    if (lane == 0) red[wave] = sum;
    __syncthreads();
    if (tid == 0) {
        float s = 0.f;
        for (int w = 0; w < 8; ++w) s += red[w];
        red[0] = s;
    }
    __syncthreads();
    const float S = red[0];
    for (int i = tid; i < VV; i += 512) outrow[i] = lg[i] / S;
}

extern "C" void kernel_launch(void* const* d_in, const int* in_sizes, int n_in,
                              void* d_out, int out_size, void* d_ws, size_t ws_size,
                              hipStream_t stream)
{
    const float* latent = (const float*)d_in[0];
    const float* nodef  = (const float*)d_in[1];
    const int* node_ids = (const int*)d_in[2];
    const int* next_ids = (const int*)d_in[3];
    const int* stops    = (const int*)d_in[4];
    const int* lsteps   = (const int*)d_in[5];
    const int* reall    = (const int*)d_in[6];
    const float* Wz   = (const float*)d_in[7];
    const float* Wzb  = (const float*)d_in[8];
    const float* Urw  = (const float*)d_in[9];
    const float* Wr   = (const float*)d_in[10];
    const float* Wrb  = (const float*)d_in[11];
    const float* Wh   = (const float*)d_in[12];
    const float* Whb  = (const float*)d_in[13];
    const float* Wd12 = (const float*)d_in[14];
    const float* Wd12b= (const float*)d_in[15];
    const float* Wd3  = (const float*)d_in[16];
    const float* Wd3b = (const float*)d_in[17];
    const float* Ud   = (const float*)d_in[18];
    const float* Udb  = (const float*)d_in[19];
    const float* Wl   = (const float*)d_in[20];
    const float* Wlb  = (const float*)d_in[21];
    const float* Ul   = (const float*)d_in[22];
    const float* Ulb  = (const float*)d_in[23];
    (void)in_sizes; (void)n_in; (void)out_size; (void)ws_size;
    float* out = (float*)d_out;
    float* W = (float*)d_ws;

    size_t o = 0;
    float* Sm     = W + o; o += NN * HH;
    float* WzSm   = W + o; o += NN * HH;
    float* Wd3Sm  = W + o; o += NN * HH;
    float* WhRs   = W + o; o += NN * HH;
    int*   Cnt    = (int*)(W + o); o += NN;
    unsigned* bar = (unsigned*)(W + o); o += 64;
    const size_t zero_floats = o;           // everything above must start at 0
    int*   vid    = (int*)(W + o); o += NN;
    int*   excl   = (int*)(W + o); o += LL + 1;
    float* cz     = W + o; o += NN * HH;
    float* r1s    = W + o; o += NN * HH;
    float* sig0   = W + o; o += NN * HH;
    float* ch     = W + o; o += NN * HH;
    float* WhSig0 = W + o; o += NN * HH;
    float* dotd12 = W + o; o += NN;
    float* NewH   = W + o; o += (size_t)LL * HH;
    float* WzM    = W + o; o += (size_t)LL * HH;
    float* WhSv   = W + o; o += (size_t)LL * HH;
    float* UrM    = W + o; o += HH + 64;

    hipMemsetAsync(W, 0, zero_floats * sizeof(float), stream);
    k_vid   <<<NN, 256, 0, stream>>>(nodef, vid);
    k_consts<<<NN, 512, 0, stream>>>(vid, latent, Wz, Wzb, Wr, Wrb, Wh, Whb,
                                     Wd12, Wd12b, Ud, cz, r1s, sig0, ch, dotd12);
    k_whsig0<<<NN, 512, 0, stream>>>(Wh, sig0, WhSig0);
    k_excl  <<<LL, 256, 0, stream>>>(node_ids, next_ids, excl);
    k_copy  <<<2, 256, 0, stream>>>(stops, reall, out);
    k_seq   <<<GSEQ, TSEQ, 0, stream>>>(node_ids, excl, Urw, Wz, Wh, Wd3, Wd3b, Ud, Udb,
                                        cz, r1s, ch, WhSig0, dotd12,
                                        Sm, WzSm, Wd3Sm, WhRs, Cnt,
                                        NewH, WzM, WhSv, UrM, out + LL, bar);
    k_label <<<NN, 512, 0, stream>>>(latent, lsteps, NewH, Wl, Wlb, Ul, Ulb, out);
}

// Round 2
// 5449.901 us; speedup vs baseline: 2.0283x; 2.0283x over previous
//
#include <hip/hip_runtime.h>
#include <math.h>

// Problem constants (fixed by setup_inputs)
#define NN   256   // nodes
#define HH   450   // hidden
#define LATD 56    // latent
#define VV   780   // vocab
#define LL   511   // path length (2N-1)
#define GSEQ 32    // persistent blocks
#define TSEQ 512   // threads per persistent block
#define SLOTPAD 16 // 64B padding between barrier slots
#define KMAX 15    // max k-slice per block (450 = 14*32 + 2)

__device__ __forceinline__ float wred_sum(float v) {
    for (int off = 32; off; off >>= 1) v += __shfl_down(v, off, 64);
    return v;
}

// ---- single-stage all-poll grid barrier (monotonic phase counter) ----
__device__ __forceinline__ void gridbar(unsigned* slots, unsigned ph) {
    __syncthreads();   // compiler drains vmcnt before s_barrier
    const int tid = threadIdx.x;
    if (tid == 0) {
        __threadfence();   // release: write back this XCD's L2
        __hip_atomic_store(&slots[blockIdx.x * SLOTPAD], ph,
                           __ATOMIC_RELAXED, __HIP_MEMORY_SCOPE_AGENT);
    }
    if (tid < GSEQ) {
        while (__hip_atomic_load(&slots[tid * SLOTPAD],
                                 __ATOMIC_RELAXED, __HIP_MEMORY_SCOPE_AGENT) < ph) {
            __builtin_amdgcn_s_sleep(1);
        }
        __threadfence();   // acquire: invalidate stale lines (CU/XCD-wide)
    }
    __syncthreads();
}

// ---- find vocab id of each node's one-hot feature ----
__global__ void k_vid(const float* __restrict__ nf, int* __restrict__ vid) {
    const int u = blockIdx.x;
    for (int v = threadIdx.x; v < VV; v += blockDim.x)
        if (nf[(size_t)u * VV + v] > 0.5f) vid[u] = v;
}

// ---- per-node constants: cz, r1, sigma(r1), ch, and Ud . relu(d12) scalar ----
__global__ __launch_bounds__(512) void k_consts(
    const int* __restrict__ vid, const float* __restrict__ latent,
    const float* __restrict__ Wz, const float* __restrict__ Wzb,
    const float* __restrict__ Wr, const float* __restrict__ Wrb,
    const float* __restrict__ Wh, const float* __restrict__ Whb,
    const float* __restrict__ Wd12, const float* __restrict__ Wd12b,
    const float* __restrict__ Ud,
    float* __restrict__ cz, float* __restrict__ r1s, float* __restrict__ sig0,
    float* __restrict__ ch, float* __restrict__ dotd12)
{
    const int u = blockIdx.x, tid = threadIdx.x;
    const int v = vid[u];
    __shared__ float red[8];
    float p = 0.f;
    if (tid < HH) {
        const int i = tid, o = u * HH + i;
        cz[o] = Wz[(size_t)i * (VV + HH) + v] + Wzb[i];
        const float r1 = Wr[(size_t)i * VV + v] + Wrb[i];
        r1s[o] = r1;
        sig0[o] = 1.f / (1.f + expf(-r1));
        ch[o] = Wh[(size_t)i * (VV + HH) + v] + Whb[i];
        float d = Wd12[(size_t)i * (VV + LATD) + v] + Wd12b[i];
        for (int k = 0; k < LATD; ++k)
            d += Wd12[(size_t)i * (VV + LATD) + VV + k] * latent[k];
        p = Ud[i] * fmaxf(d, 0.f);
    }
    p = wred_sum(p);
    if ((tid & 63) == 0) red[tid >> 6] = p;
    __syncthreads();
    if (tid == 0) {
        float s = 0.f;
        for (int w = 0; w < 8; ++w) s += red[w];
        dotd12[u] = s;
    }
}

// ---- WhSig0[u] = Wh_H @ sigma(r1[u]) ----
__global__ __launch_bounds__(512) void k_whsig0(
    const float* __restrict__ Wh, const float* __restrict__ sig0, float* __restrict__ out)
{
    const int u = blockIdx.x, tid = threadIdx.x, wave = tid >> 6, lane = tid & 63;
    __shared__ float sg[HH];
    if (tid < HH) sg[tid] = sig0[u * HH + tid];
    __syncthreads();
    for (int r = wave; r < HH; r += 8) {
        float acc = 0.f;
        for (int k = lane; k < HH; k += 64)
            acc += Wh[(size_t)r * (VV + HH) + VV + k] * sg[k];
        acc = wred_sum(acc);
        if (lane == 0) out[u * HH + r] = acc;
    }
}

// ---- pretranspose Wh_H: WhT[k][r] = Wh[r][VV+k] ----
__global__ void k_wht(const float* __restrict__ Wh, float* __restrict__ WhT) {
    const int k = blockIdx.x;
    for (int r = threadIdx.x; r < HH; r += blockDim.x)
        WhT[(size_t)k * HH + r] = Wh[(size_t)r * (VV + HH) + VV + k];
}

// ---- per-step exclusion index: step t' < t that created message b_t -> a_t ----
__global__ void k_excl(const int* __restrict__ node_ids, const int* __restrict__ next_ids,
                       int* __restrict__ excl)
{
    const int t = blockIdx.x;
    if (threadIdx.x == 0) excl[t] = -1;
    __syncthreads();
    const int a = node_ids[t], b = next_ids[t];
    for (int tp = threadIdx.x; tp < t; tp += blockDim.x)
        if (node_ids[tp] == b && next_ids[tp] == a) excl[t] = tp;
}

// ---- copy stops and real_labels into d_out as float ----
__global__ void k_copy(const int* __restrict__ stops, const int* __restrict__ reall,
                       float* __restrict__ out)
{
    const int i = blockIdx.x * blockDim.x + threadIdx.x;
    if (i < LL) out[i] = (float)stops[i];
    if (i < NN) out[2 * LL + i] = (float)reall[i];
}

// ---- the sequential scan: persistent kernel, ONE grid barrier per step ----
// Column-partitioned Wh fan-in: block b owns k in [kbeg, kbeg+kcnt).
//   UrM[k] from LDS Ur rows -> sigma_k -> partial[r] = sum_k WhT[k][r]*sigma_k
//   -> atomicAdd into WhSv[t-1][r] and WhRs[a_t][r].
// Wz/Wd3 row slices: plain owner RMW (same index partition).
__global__ __launch_bounds__(TSEQ) void k_seq(
    const int* __restrict__ node_ids, const int* __restrict__ excl,
    const float* __restrict__ Ur, const float* __restrict__ Wz,
    const float* __restrict__ WhT, const float* __restrict__ Wd3,
    const float* __restrict__ Wd3b, const float* __restrict__ Ud,
    const float* __restrict__ Udb,
    const float* __restrict__ cz, const float* __restrict__ r1s,
    const float* __restrict__ ch, const float* __restrict__ WhSig0,
    const float* __restrict__ dotd12,
    float* __restrict__ Sm, float* __restrict__ WzSm,
    float* __restrict__ Wd3Sm, float* __restrict__ WhRs,
    float* __restrict__ WhSv, int* __restrict__ Cnt,
    float* __restrict__ NewH, float* __restrict__ WzM,
    float* __restrict__ pred_out, unsigned* __restrict__ bar)
{
    const int tid = threadIdx.x, bid = blockIdx.x;
    const int wave = tid >> 6, lane = tid & 63;
    const int kcnt = 14 + (bid < 2 ? 1 : 0);
    const int kbeg = 14 * bid + (bid < 2 ? bid : 2);

    __shared__ float Ur_s[KMAX * HH];    // 27 KB: rows kbeg..kbeg+kcnt of Ur
    __shared__ float WhT_s[KMAX * HH];   // 27 KB: rows kbeg..kbeg+kcnt of WhT
    __shared__ float nh_s[HH];
    __shared__ float sig_s[KMAX];
    __shared__ float psred[TSEQ / 64];

    // Preload weight slices (rows are contiguous -> flat coalesced copy)
    for (int i = tid; i < kcnt * HH; i += TSEQ) {
        Ur_s[i]  = Ur[(size_t)kbeg * HH + i];
        WhT_s[i] = WhT[(size_t)kbeg * HH + i];
    }
    __syncthreads();

    unsigned ph = 0;
    for (int t = 1; t <= LL; ++t) {
        const int ap  = node_ids[t - 1];
        const int idx = excl[t - 1];
        // ---- new_h(t-1), redundantly in every block ----
        if (tid < HH) {
            const int o = ap * HH + tid;
            float zarg = WzSm[o] + cz[o];
            float whv  = WhRs[o] + ch[o];
            float sv   = Sm[o];
            float e = 0.f;
            if (idx >= 0) {
                const int oe = idx * HH + tid;
                zarg -= WzM[oe]; whv -= WhSv[oe]; sv -= NewH[oe];
                e = 1.f;
            }
            const float cc = 256.f - (float)Cnt[ap] + e;
            whv += cc * WhSig0[o];
            const float z = 1.f / (1.f + expf(-zarg));
            nh_s[tid] = (1.f - z) * sv + z * tanhf(whv);
        }
        if (bid == 0) {  // pred_stop(t-1)
            float ps = 0.f;
            if (tid < HH)
                ps = Ud[HH + tid] * fmaxf(Wd3Sm[ap * HH + tid] + Wd3b[tid], 0.f);
            ps = wred_sum(ps);
            if (lane == 0) psred[wave] = ps;
        }
        __syncthreads();
        if (bid == 0) {
            if (tid < HH) NewH[(size_t)(t - 1) * HH + tid] = nh_s[tid];
            if (tid == 0) {
                float s = 0.f;
                for (int w = 0; w < TSEQ / 64; ++w) s += psred[w];
                pred_out[t - 1] = s + dotd12[ap] + Udb[0];
            }
        }
        if (t == LL) break;   // last step: no ingestion (is_last masked)

        const int a = node_ids[t];
        if (bid == 1 && tid < HH) Sm[a * HH + tid] += nh_s[tid];
        if (bid == 0 && tid == 0) Cnt[a] += 1;

        // ---- UrM slice + sigma (LDS weights) ----
        for (int j = wave; j < kcnt; j += TSEQ / 64) {
            float acc = 0.f;
            for (int c = lane; c < HH; c += 64) acc += Ur_s[j * HH + c] * nh_s[c];
            acc = wred_sum(acc);
            if (lane == 0) {
                const int k = kbeg + j;
                sig_s[j] = 1.f / (1.f + expf(-(acc + r1s[a * HH + k])));
            }
        }
        // ---- Wz / Wd3 row slices (L2-resident weights, owner RMW) ----
        for (int j = wave; j < 2 * kcnt; j += TSEQ / 64) {
            const int jj = (j < kcnt) ? j : j - kcnt;
            const int i = kbeg + jj;
            const float* wrow = (j < kcnt) ? (Wz + (size_t)i * (VV + HH) + VV)
                                           : (Wd3 + (size_t)i * HH);
            float acc = 0.f;
            for (int c = lane; c < HH; c += 64) acc += wrow[c] * nh_s[c];
            acc = wred_sum(acc);
            if (lane == 0) {
                if (j < kcnt) { WzM[(size_t)(t - 1) * HH + i] = acc; WzSm[a * HH + i] += acc; }
                else          Wd3Sm[a * HH + i] += acc;
            }
        }
        __syncthreads();
        // ---- partial Wh fan-in: column slice against all 450 rows ----
        if (tid < HH) {
            float acc = 0.f;
            for (int j = 0; j < kcnt; ++j) acc += WhT_s[j * HH + tid] * sig_s[j];
            __hip_atomic_fetch_add(&WhRs[a * HH + tid], acc,
                                   __ATOMIC_RELAXED, __HIP_MEMORY_SCOPE_AGENT);
            __hip_atomic_fetch_add(&WhSv[(size_t)(t - 1) * HH + tid], acc,
                                   __ATOMIC_RELAXED, __HIP_MEMORY_SCOPE_AGENT);
        }
        gridbar(bar, ++ph);
    }
}

// ---- labels: root (q=0, outer relu, no softmax) + 255 label steps (softmax) ----
__global__ __launch_bounds__(512) void k_label(
    const float* __restrict__ latent, const int* __restrict__ lsteps,
    const float* __restrict__ NewH,
    const float* __restrict__ Wl, const float* __restrict__ Wlb,
    const float* __restrict__ Ul, const float* __restrict__ Ulb,
    float* __restrict__ out)
{
    const int q = blockIdx.x, tid = threadIdx.x, wave = tid >> 6, lane = tid & 63;
    __shared__ float inp[LATD + HH];
    __shared__ float t2[HH];
    __shared__ float lg[VV];
    __shared__ float red[8];
    if (tid < LATD) inp[tid] = latent[tid];
    if (q == 0) {
        if (tid < HH) inp[LATD + tid] = 0.f;
    } else {
        const int t = lsteps[q - 1];
        if (tid < HH) inp[LATD + tid] = NewH[(size_t)t * HH + tid];
    }
    __syncthreads();
    for (int r = wave; r < HH; r += 8) {
        float acc = 0.f;
        for (int k = lane; k < LATD + HH; k += 64)
            acc += Wl[(size_t)r * (LATD + HH) + k] * inp[k];
        acc = wred_sum(acc);
        if (lane == 0) {
            const float v = acc + Wlb[r];
            t2[r] = (q == 0) ? v : fmaxf(v, 0.f);   // root: no inner relu
        }
    }
    __syncthreads();
    for (int r = wave; r < VV; r += 8) {
        float acc = 0.f;
        for (int k = lane; k < HH; k += 64) acc += Ul[(size_t)r * HH + k] * t2[k];
        acc = wred_sum(acc);
        if (lane == 0) lg[r] = acc + Ulb[r];
    }
    __syncthreads();
    float* outrow = out + 2 * LL + NN + (size_t)q * VV;
    if (q == 0) {   // root: relu, no softmax
        for (int i = tid; i < VV; i += 512) outrow[i] = fmaxf(lg[i], 0.f);
        return;
    }
    float mx = -1e30f;
    for (int i = tid; i < VV; i += 512) mx = fmaxf(mx, lg[i]);
    for (int off = 32; off; off >>= 1) mx = fmaxf(mx, __shfl_down(mx, off, 64));
    if (lane == 0) red[wave] = mx;
    __syncthreads();
    if (tid == 0) {
        float m = red[0];
        for (int w = 1; w < 8; ++w) m = fmaxf(m, red[w]);
        red[0] = m;
    }
    __syncthreads();
    const float M = red[0];
    float sum = 0.f;
    for (int i = tid; i < VV; i += 512) { const float e = expf(lg[i] - M); lg[i] = e; sum += e; }
    __syncthreads();
    sum = wred_sum(sum);
    if (lane == 0) red[wave] = sum;
    __syncthreads();
    if (tid == 0) {
        float s = 0.f;
        for (int w = 0; w < 8; ++w) s += red[w];
        red[0] = s;
    }
    __syncthreads();
    const float S = red[0];
    for (int i = tid; i < VV; i += 512) outrow[i] = lg[i] / S;
}

extern "C" void kernel_launch(void* const* d_in, const int* in_sizes, int n_in,
                              void* d_out, int out_size, void* d_ws, size_t ws_size,
                              hipStream_t stream)
{
    const float* latent = (const float*)d_in[0];
    const float* nodef  = (const float*)d_in[1];
    const int* node_ids = (const int*)d_in[2];
    const int* next_ids = (const int*)d_in[3];
    const int* stops    = (const int*)d_in[4];
    const int* lsteps   = (const int*)d_in[5];
    const int* reall    = (const int*)d_in[6];
    const float* Wz   = (const float*)d_in[7];
    const float* Wzb  = (const float*)d_in[8];
    const float* Urw  = (const float*)d_in[9];
    const float* Wr   = (const float*)d_in[10];
    const float* Wrb  = (const float*)d_in[11];
    const float* Wh   = (const float*)d_in[12];
    const float* Whb  = (const float*)d_in[13];
    const float* Wd12 = (const float*)d_in[14];
    const float* Wd12b= (const float*)d_in[15];
    const float* Wd3  = (const float*)d_in[16];
    const float* Wd3b = (const float*)d_in[17];
    const float* Ud   = (const float*)d_in[18];
    const float* Udb  = (const float*)d_in[19];
    const float* Wl   = (const float*)d_in[20];
    const float* Wlb  = (const float*)d_in[21];
    const float* Ul   = (const float*)d_in[22];
    const float* Ulb  = (const float*)d_in[23];
    (void)in_sizes; (void)n_in; (void)out_size; (void)ws_size;
    float* out = (float*)d_out;
    float* W = (float*)d_ws;

    size_t o = 0;
    float* Sm     = W + o; o += NN * HH;
    float* WzSm   = W + o; o += NN * HH;
    float* Wd3Sm  = W + o; o += NN * HH;
    float* WhRs   = W + o; o += NN * HH;
    float* WhSv   = W + o; o += (size_t)LL * HH;   // atomic fan-in target: must be 0
    int*   Cnt    = (int*)(W + o); o += NN;
    unsigned* bar = (unsigned*)(W + o); o += GSEQ * SLOTPAD;
    const size_t zero_floats = o;           // everything above must start at 0
    int*   vid    = (int*)(W + o); o += NN;
    int*   excl   = (int*)(W + o); o += LL + 1;
    float* cz     = W + o; o += NN * HH;
    float* r1s    = W + o; o += NN * HH;
    float* sig0   = W + o; o += NN * HH;
    float* ch     = W + o; o += NN * HH;
    float* WhSig0 = W + o; o += NN * HH;
    float* dotd12 = W + o; o += NN;
    float* WhT    = W + o; o += (size_t)HH * HH;
    float* NewH   = W + o; o += (size_t)LL * HH;
    float* WzM    = W + o; o += (size_t)LL * HH;

    hipMemsetAsync(W, 0, zero_floats * sizeof(float), stream);
    k_vid   <<<NN, 256, 0, stream>>>(nodef, vid);
    k_consts<<<NN, 512, 0, stream>>>(vid, latent, Wz, Wzb, Wr, Wrb, Wh, Whb,
                                     Wd12, Wd12b, Ud, cz, r1s, sig0, ch, dotd12);
    k_whsig0<<<NN, 512, 0, stream>>>(Wh, sig0, WhSig0);
    k_wht   <<<HH, 256, 0, stream>>>(Wh, WhT);
    k_excl  <<<LL, 256, 0, stream>>>(node_ids, next_ids, excl);
    k_copy  <<<2, 256, 0, stream>>>(stops, reall, out);
    k_seq   <<<GSEQ, TSEQ, 0, stream>>>(node_ids, excl, Urw, Wz, WhT, Wd3, Wd3b, Ud, Udb,
                                        cz, r1s, ch, WhSig0, dotd12,
                                        Sm, WzSm, Wd3Sm, WhRs, WhSv, Cnt,
                                        NewH, WzM, out + LL, bar);
    k_label <<<NN, 512, 0, stream>>>(latent, lsteps, NewH, Wl, Wlb, Ul, Ulb, out);
}

// Round 3
// 5431.062 us; speedup vs baseline: 2.0353x; 1.0035x over previous
//
#include <hip/hip_runtime.h>
#include <math.h>

// Problem constants (fixed by setup_inputs)
#define NN   256   // nodes
#define HH   450   // hidden
#define LATD 56    // latent
#define VV   780   // vocab
#define LL   511   // path length (2N-1)
#define GSEQ 32    // persistent blocks
#define TSEQ 512   // threads per persistent block
#define SLOTPAD 16 // 64B padding between barrier slots
#define KMAX 15    // max k-slice per block (450 = 14*32 + 2)

__device__ __forceinline__ float wred_sum(float v) {
    for (int off = 32; off; off >>= 1) v += __shfl_down(v, off, 64);
    return v;
}

// ---- agent-scope relaxed atomic helpers (coherent through L3, no fences) ----
__device__ __forceinline__ float aload(const float* p) {
    return __hip_atomic_load(p, __ATOMIC_RELAXED, __HIP_MEMORY_SCOPE_AGENT);
}
__device__ __forceinline__ void astore(float* p, float v) {
    __hip_atomic_store(p, v, __ATOMIC_RELAXED, __HIP_MEMORY_SCOPE_AGENT);
}
__device__ __forceinline__ void aadd(float* p, float v) {
    (void)__hip_atomic_fetch_add(p, v, __ATOMIC_RELAXED, __HIP_MEMORY_SCOPE_AGENT);
}

// ---- fence-free grid barrier: all communication is agent-scope atomic ----
// Pre-barrier per-thread s_waitcnt (explicit + the compiler's own before
// s_barrier) guarantees this block's L3 writes have landed before publish.
__device__ __forceinline__ void gridbar(unsigned* slots, unsigned ph) {
    asm volatile("s_waitcnt vmcnt(0)" ::: "memory");
    __syncthreads();
    const int tid = threadIdx.x;
    if (tid == 0)
        __hip_atomic_store(&slots[blockIdx.x * SLOTPAD], ph,
                           __ATOMIC_RELAXED, __HIP_MEMORY_SCOPE_AGENT);
    if (tid < GSEQ) {
        while (__hip_atomic_load(&slots[tid * SLOTPAD],
                                 __ATOMIC_RELAXED, __HIP_MEMORY_SCOPE_AGENT) < ph) {
            __builtin_amdgcn_s_sleep(1);
        }
    }
    __syncthreads();
}

// ---- find vocab id of each node's one-hot feature ----
__global__ void k_vid(const float* __restrict__ nf, int* __restrict__ vid) {
    const int u = blockIdx.x;
    for (int v = threadIdx.x; v < VV; v += blockDim.x)
        if (nf[(size_t)u * VV + v] > 0.5f) vid[u] = v;
}

// ---- per-node constants: cz, r1, sigma(r1), ch, and Ud . relu(d12) scalar ----
__global__ __launch_bounds__(512) void k_consts(
    const int* __restrict__ vid, const float* __restrict__ latent,
    const float* __restrict__ Wz, const float* __restrict__ Wzb,
    const float* __restrict__ Wr, const float* __restrict__ Wrb,
    const float* __restrict__ Wh, const float* __restrict__ Whb,
    const float* __restrict__ Wd12, const float* __restrict__ Wd12b,
    const float* __restrict__ Ud,
    float* __restrict__ cz, float* __restrict__ r1s, float* __restrict__ sig0,
    float* __restrict__ ch, float* __restrict__ dotd12)
{
    const int u = blockIdx.x, tid = threadIdx.x;
    const int v = vid[u];
    __shared__ float red[8];
    float p = 0.f;
    if (tid < HH) {
        const int i = tid, o = u * HH + i;
        cz[o] = Wz[(size_t)i * (VV + HH) + v] + Wzb[i];
        const float r1 = Wr[(size_t)i * VV + v] + Wrb[i];
        r1s[o] = r1;
        sig0[o] = 1.f / (1.f + expf(-r1));
        ch[o] = Wh[(size_t)i * (VV + HH) + v] + Whb[i];
        float d = Wd12[(size_t)i * (VV + LATD) + v] + Wd12b[i];
        for (int k = 0; k < LATD; ++k)
            d += Wd12[(size_t)i * (VV + LATD) + VV + k] * latent[k];
        p = Ud[i] * fmaxf(d, 0.f);
    }
    p = wred_sum(p);
    if ((tid & 63) == 0) red[tid >> 6] = p;
    __syncthreads();
    if (tid == 0) {
        float s = 0.f;
        for (int w = 0; w < 8; ++w) s += red[w];
        dotd12[u] = s;
    }
}

// ---- WhSig0[u] = Wh_H @ sigma(r1[u]) ----
__global__ __launch_bounds__(512) void k_whsig0(
    const float* __restrict__ Wh, const float* __restrict__ sig0, float* __restrict__ out)
{
    const int u = blockIdx.x, tid = threadIdx.x, wave = tid >> 6, lane = tid & 63;
    __shared__ float sg[HH];
    if (tid < HH) sg[tid] = sig0[u * HH + tid];
    __syncthreads();
    for (int r = wave; r < HH; r += 8) {
        float acc = 0.f;
        for (int k = lane; k < HH; k += 64)
            acc += Wh[(size_t)r * (VV + HH) + VV + k] * sg[k];
        acc = wred_sum(acc);
        if (lane == 0) out[u * HH + r] = acc;
    }
}

// ---- pretranspose Wh_H: WhT[k][r] = Wh[r][VV+k] ----
__global__ void k_wht(const float* __restrict__ Wh, float* __restrict__ WhT) {
    const int k = blockIdx.x;
    for (int r = threadIdx.x; r < HH; r += blockDim.x)
        WhT[(size_t)k * HH + r] = Wh[(size_t)r * (VV + HH) + VV + k];
}

// ---- per-step exclusion index + precomputed neighbor-count coefficient ----
// excl[t]  = step t' < t that created message b_t -> a_t (or -1)
// ccpre[t] = 256 - #{u in [1,t]: node_ids[u]==node_ids[t]} + (excl[t]>=0 ? 1 : 0)
__global__ void k_excl(const int* __restrict__ node_ids, const int* __restrict__ next_ids,
                       int* __restrict__ excl, float* __restrict__ ccpre)
{
    const int t = blockIdx.x;
    __shared__ int ex, cnt;
    if (threadIdx.x == 0) { ex = -1; cnt = 0; }
    __syncthreads();
    const int a = node_ids[t], b = next_ids[t];
    for (int tp = threadIdx.x; tp <= t; tp += blockDim.x) {
        if (tp < t && node_ids[tp] == b && next_ids[tp] == a) ex = tp;
        if (tp >= 1 && node_ids[tp] == a) atomicAdd(&cnt, 1);
    }
    __syncthreads();
    if (threadIdx.x == 0) {
        excl[t] = ex;
        ccpre[t] = 256.f - (float)cnt + (ex >= 0 ? 1.f : 0.f);
    }
}

// ---- copy stops and real_labels into d_out as float ----
__global__ void k_copy(const int* __restrict__ stops, const int* __restrict__ reall,
                       float* __restrict__ out)
{
    const int i = blockIdx.x * blockDim.x + threadIdx.x;
    if (i < LL) out[i] = (float)stops[i];
    if (i < NN) out[2 * LL + i] = (float)reall[i];
}

// ---- the sequential scan: persistent kernel, ONE fence-free barrier/step ----
// All mutable cross-block state goes through agent-scope relaxed atomics
// (coherent at L3); read-only weights stay hot in LDS/L1/L2 forever.
__global__ __launch_bounds__(TSEQ) void k_seq(
    const int* __restrict__ node_ids, const int* __restrict__ excl,
    const float* __restrict__ ccpre,
    const float* __restrict__ Ur, const float* __restrict__ Wz,
    const float* __restrict__ WhT, const float* __restrict__ Wd3,
    const float* __restrict__ Wd3b, const float* __restrict__ Ud,
    const float* __restrict__ Udb,
    const float* __restrict__ cz, const float* __restrict__ r1s,
    const float* __restrict__ ch, const float* __restrict__ WhSig0,
    const float* __restrict__ dotd12,
    float* __restrict__ Sm, float* __restrict__ WzSm,
    float* __restrict__ Wd3Sm, float* __restrict__ WhRs,
    float* __restrict__ WhSv,
    float* __restrict__ NewH, float* __restrict__ WzM,
    float* __restrict__ pred_out, unsigned* __restrict__ bar)
{
    const int tid = threadIdx.x, bid = blockIdx.x;
    const int wave = tid >> 6, lane = tid & 63;
    const int kcnt = 14 + (bid < 2 ? 1 : 0);
    const int kbeg = 14 * bid + (bid < 2 ? bid : 2);

    __shared__ float Ur_s[KMAX * HH];    // 27 KB: rows kbeg.. of Ur
    __shared__ float WhT_s[KMAX * HH];   // 27 KB: rows kbeg.. of WhT
    __shared__ float nh_s[HH];
    __shared__ float sig_s[KMAX];
    __shared__ float psred[TSEQ / 64];

    for (int i = tid; i < kcnt * HH; i += TSEQ) {
        Ur_s[i]  = Ur[(size_t)kbeg * HH + i];
        WhT_s[i] = WhT[(size_t)kbeg * HH + i];
    }
    __syncthreads();

    unsigned ph = 0;
    for (int t = 1; t <= LL; ++t) {
        const int ap  = node_ids[t - 1];
        const int idx = excl[t - 1];
        // ---- new_h(t-1), redundantly in every block (atomic loads -> L3) ----
        if (tid < HH) {
            const int o = ap * HH + tid;
            float zarg = aload(&WzSm[o]) + cz[o];
            float whv  = aload(&WhRs[o]) + ch[o];
            float sv   = aload(&Sm[o]);
            if (idx >= 0) {
                const int oe = idx * HH + tid;
                zarg -= aload(&WzM[oe]);
                whv  -= aload(&WhSv[oe]);
                sv   -= aload(&NewH[oe]);
            }
            whv += ccpre[t - 1] * WhSig0[o];
            const float z = 1.f / (1.f + expf(-zarg));
            nh_s[tid] = (1.f - z) * sv + z * tanhf(whv);
        }
        if (bid == 0) {  // pred_stop(t-1)
            float ps = 0.f;
            if (tid < HH)
                ps = Ud[HH + tid] * fmaxf(aload(&Wd3Sm[ap * HH + tid]) + Wd3b[tid], 0.f);
            ps = wred_sum(ps);
            if (lane == 0) psred[wave] = ps;
        }
        __syncthreads();
        if (bid == 0) {
            if (tid < HH) astore(&NewH[(size_t)(t - 1) * HH + tid], nh_s[tid]);
            if (tid == 0) {
                float s = 0.f;
                for (int w = 0; w < TSEQ / 64; ++w) s += psred[w];
                pred_out[t - 1] = s + dotd12[ap] + Udb[0];
            }
        }
        if (t == LL) break;   // last step: no ingestion (is_last masked)

        const int a = node_ids[t];
        if (bid == 1 && tid < HH) aadd(&Sm[a * HH + tid], nh_s[tid]);

        // ---- UrM slice + sigma (LDS weights) ----
        for (int j = wave; j < kcnt; j += TSEQ / 64) {
            float acc = 0.f;
            for (int c = lane; c < HH; c += 64) acc += Ur_s[j * HH + c] * nh_s[c];
            acc = wred_sum(acc);
            if (lane == 0) {
                const int k = kbeg + j;
                sig_s[j] = 1.f / (1.f + expf(-(acc + r1s[a * HH + k])));
            }
        }
        // ---- Wz / Wd3 row slices (L2-resident weights, owner updates) ----
        for (int j = wave; j < 2 * kcnt; j += TSEQ / 64) {
            const int jj = (j < kcnt) ? j : j - kcnt;
            const int i = kbeg + jj;
            const float* wrow = (j < kcnt) ? (Wz + (size_t)i * (VV + HH) + VV)
                                           : (Wd3 + (size_t)i * HH);
            float acc = 0.f;
            for (int c = lane; c < HH; c += 64) acc += wrow[c] * nh_s[c];
            acc = wred_sum(acc);
            if (lane == 0) {
                if (j < kcnt) { astore(&WzM[(size_t)(t - 1) * HH + i], acc);
                                aadd(&WzSm[a * HH + i], acc); }
                else          aadd(&Wd3Sm[a * HH + i], acc);
            }
        }
        __syncthreads();
        // ---- partial Wh fan-in: column slice against all 450 rows ----
        if (tid < HH) {
            float acc = 0.f;
            for (int j = 0; j < kcnt; ++j) acc += WhT_s[j * HH + tid] * sig_s[j];
            aadd(&WhRs[a * HH + tid], acc);
            aadd(&WhSv[(size_t)(t - 1) * HH + tid], acc);
        }
        gridbar(bar, ++ph);
    }
}

// ---- labels: root (q=0, outer relu, no softmax) + 255 label steps (softmax) ----
__global__ __launch_bounds__(512) void k_label(
    const float* __restrict__ latent, const int* __restrict__ lsteps,
    const float* __restrict__ NewH,
    const float* __restrict__ Wl, const float* __restrict__ Wlb,
    const float* __restrict__ Ul, const float* __restrict__ Ulb,
    float* __restrict__ out)
{
    const int q = blockIdx.x, tid = threadIdx.x, wave = tid >> 6, lane = tid & 63;
    __shared__ float inp[LATD + HH];
    __shared__ float t2[HH];
    __shared__ float lg[VV];
    __shared__ float red[8];
    if (tid < LATD) inp[tid] = latent[tid];
    if (q == 0) {
        if (tid < HH) inp[LATD + tid] = 0.f;
    } else {
        const int t = lsteps[q - 1];
        if (tid < HH) inp[LATD + tid] = NewH[(size_t)t * HH + tid];
    }
    __syncthreads();
    for (int r = wave; r < HH; r += 8) {
        float acc = 0.f;
        for (int k = lane; k < LATD + HH; k += 64)
            acc += Wl[(size_t)r * (LATD + HH) + k] * inp[k];
        acc = wred_sum(acc);
        if (lane == 0) {
            const float v = acc + Wlb[r];
            t2[r] = (q == 0) ? v : fmaxf(v, 0.f);   // root: no inner relu
        }
    }
    __syncthreads();
    for (int r = wave; r < VV; r += 8) {
        float acc = 0.f;
        for (int k = lane; k < HH; k += 64) acc += Ul[(size_t)r * HH + k] * t2[k];
        acc = wred_sum(acc);
        if (lane == 0) lg[r] = acc + Ulb[r];
    }
    __syncthreads();
    float* outrow = out + 2 * LL + NN + (size_t)q * VV;
    if (q == 0) {   // root: relu, no softmax
        for (int i = tid; i < VV; i += 512) outrow[i] = fmaxf(lg[i], 0.f);
        return;
    }
    float mx = -1e30f;
    for (int i = tid; i < VV; i += 512) mx = fmaxf(mx, lg[i]);
    for (int off = 32; off; off >>= 1) mx = fmaxf(mx, __shfl_down(mx, off, 64));
    if (lane == 0) red[wave] = mx;
    __syncthreads();
    if (tid == 0) {
        float m = red[0];
        for (int w = 1; w < 8; ++w) m = fmaxf(m, red[w]);
        red[0] = m;
    }
    __syncthreads();
    const float M = red[0];
    float sum = 0.f;
    for (int i = tid; i < VV; i += 512) { const float e = expf(lg[i] - M); lg[i] = e; sum += e; }
    __syncthreads();
    sum = wred_sum(sum);
    if (lane == 0) red[wave] = sum;
    __syncthreads();
    if (tid == 0) {
        float s = 0.f;
        for (int w = 0; w < 8; ++w) s += red[w];
        red[0] = s;
    }
    __syncthreads();
    const float S = red[0];
    for (int i = tid; i < VV; i += 512) outrow[i] = lg[i] / S;
}

extern "C" void kernel_launch(void* const* d_in, const int* in_sizes, int n_in,
                              void* d_out, int out_size, void* d_ws, size_t ws_size,
                              hipStream_t stream)
{
    const float* latent = (const float*)d_in[0];
    const float* nodef  = (const float*)d_in[1];
    const int* node_ids = (const int*)d_in[2];
    const int* next_ids = (const int*)d_in[3];
    const int* stops    = (const int*)d_in[4];
    const int* lsteps   = (const int*)d_in[5];
    const int* reall    = (const int*)d_in[6];
    const float* Wz   = (const float*)d_in[7];
    const float* Wzb  = (const float*)d_in[8];
    const float* Urw  = (const float*)d_in[9];
    const float* Wr   = (const float*)d_in[10];
    const float* Wrb  = (const float*)d_in[11];
    const float* Wh   = (const float*)d_in[12];
    const float* Whb  = (const float*)d_in[13];
    const float* Wd12 = (const float*)d_in[14];
    const float* Wd12b= (const float*)d_in[15];
    const float* Wd3  = (const float*)d_in[16];
    const float* Wd3b = (const float*)d_in[17];
    const float* Ud   = (const float*)d_in[18];
    const float* Udb  = (const float*)d_in[19];
    const float* Wl   = (const float*)d_in[20];
    const float* Wlb  = (const float*)d_in[21];
    const float* Ul   = (const float*)d_in[22];
    const float* Ulb  = (const float*)d_in[23];
    (void)in_sizes; (void)n_in; (void)out_size; (void)ws_size;
    float* out = (float*)d_out;
    float* W = (float*)d_ws;

    size_t o = 0;
    float* Sm     = W + o; o += NN * HH;
    float* WzSm   = W + o; o += NN * HH;
    float* Wd3Sm  = W + o; o += NN * HH;
    float* WhRs   = W + o; o += NN * HH;
    float* WhSv   = W + o; o += (size_t)LL * HH;   // atomic fan-in target: must be 0
    unsigned* bar = (unsigned*)(W + o); o += GSEQ * SLOTPAD;
    const size_t zero_floats = o;           // everything above must start at 0
    int*   vid    = (int*)(W + o); o += NN;
    int*   excl   = (int*)(W + o); o += LL + 1;
    float* ccpre  = W + o; o += LL + 1;
    float* cz     = W + o; o += NN * HH;
    float* r1s    = W + o; o += NN * HH;
    float* sig0   = W + o; o += NN * HH;
    float* ch     = W + o; o += NN * HH;
    float* WhSig0 = W + o; o += NN * HH;
    float* dotd12 = W + o; o += NN;
    float* WhT    = W + o; o += (size_t)HH * HH;
    float* NewH   = W + o; o += (size_t)LL * HH;
    float* WzM    = W + o; o += (size_t)LL * HH;

    hipMemsetAsync(W, 0, zero_floats * sizeof(float), stream);
    k_vid   <<<NN, 256, 0, stream>>>(nodef, vid);
    k_consts<<<NN, 512, 0, stream>>>(vid, latent, Wz, Wzb, Wr, Wrb, Wh, Whb,
                                     Wd12, Wd12b, Ud, cz, r1s, sig0, ch, dotd12);
    k_whsig0<<<NN, 512, 0, stream>>>(Wh, sig0, WhSig0);
    k_wht   <<<HH, 256, 0, stream>>>(Wh, WhT);
    k_excl  <<<LL, 256, 0, stream>>>(node_ids, next_ids, excl, ccpre);
    k_copy  <<<2, 256, 0, stream>>>(stops, reall, out);
    k_seq   <<<GSEQ, TSEQ, 0, stream>>>(node_ids, excl, ccpre, Urw, Wz, WhT, Wd3, Wd3b,
                                        Ud, Udb, cz, r1s, ch, WhSig0, dotd12,
                                        Sm, WzSm, Wd3Sm, WhRs, WhSv,
                                        NewH, WzM, out + LL, bar);
    k_label <<<NN, 512, 0, stream>>>(latent, lsteps, NewH, Wl, Wlb, Ul, Ulb, out);
}

// Round 4
// 4053.949 us; speedup vs baseline: 2.7267x; 1.3397x over previous
//
#include <hip/hip_runtime.h>
#include <math.h>

// Problem constants (fixed by setup_inputs)
#define NN   256   // nodes
#define HH   450   // hidden
#define LATD 56    // latent
#define VV   780   // vocab
#define LL   511   // path length (2N-1)
#define GSEQ 32    // persistent blocks
#define TSEQ 512   // threads per persistent block
#define SLOTPAD 16 // barrier slot padding (u32 units)
#define KMAX 15    // max rows per block (450 = 15+15+14*30)
#define AST  16    // accumulator row stride (pad 15 -> 16)

__device__ __forceinline__ float wred_sum(float v) {
    for (int off = 32; off; off >>= 1) v += __shfl_down(v, off, 64);
    return v;
}

// ---- agent-scope relaxed atomics (UC, coherent at device level) ----
__device__ __forceinline__ void astore(float* p, float v) {
    __hip_atomic_store(p, v, __ATOMIC_RELAXED, __HIP_MEMORY_SCOPE_AGENT);
}
__device__ __forceinline__ void aadd(float* p, float v) {
    (void)__hip_atomic_fetch_add(p, v, __ATOMIC_RELAXED, __HIP_MEMORY_SCOPE_AGENT);
}
// 8-byte UC load (2 floats) — halves the UC op count vs scalar loads
__device__ __forceinline__ void uc_load2f(const float* p, float& a, float& b) {
    union { unsigned long long u; float f[2]; } cv;
    cv.u = __hip_atomic_load((const unsigned long long*)p,
                             __ATOMIC_RELAXED, __HIP_MEMORY_SCOPE_AGENT);
    a = cv.f[0]; b = cv.f[1];
}

// ---- fence-free all-poll grid barrier ----
__device__ __forceinline__ void gridbar(unsigned* slots, unsigned ph) {
    asm volatile("s_waitcnt vmcnt(0)" ::: "memory");  // drain UC publishes
    __syncthreads();
    const int tid = threadIdx.x;
    if (tid == 0)
        __hip_atomic_store(&slots[blockIdx.x * SLOTPAD], ph,
                           __ATOMIC_RELAXED, __HIP_MEMORY_SCOPE_AGENT);
    if (tid < GSEQ) {
        while (__hip_atomic_load(&slots[tid * SLOTPAD],
                                 __ATOMIC_RELAXED, __HIP_MEMORY_SCOPE_AGENT) < ph) {
            __builtin_amdgcn_s_sleep(1);
        }
    }
    __syncthreads();
}

// ---- find vocab id of each node's one-hot feature ----
__global__ void k_vid(const float* __restrict__ nf, int* __restrict__ vid) {
    const int u = blockIdx.x;
    for (int v = threadIdx.x; v < VV; v += blockDim.x)
        if (nf[(size_t)u * VV + v] > 0.5f) vid[u] = v;
}

// ---- per-node constants: cz, r1, sigma(r1), ch, and Ud . relu(d12) scalar ----
__global__ __launch_bounds__(512) void k_consts(
    const int* __restrict__ vid, const float* __restrict__ latent,
    const float* __restrict__ Wz, const float* __restrict__ Wzb,
    const float* __restrict__ Wr, const float* __restrict__ Wrb,
    const float* __restrict__ Wh, const float* __restrict__ Whb,
    const float* __restrict__ Wd12, const float* __restrict__ Wd12b,
    const float* __restrict__ Ud,
    float* __restrict__ cz, float* __restrict__ r1s, float* __restrict__ sig0,
    float* __restrict__ ch, float* __restrict__ dotd12)
{
    const int u = blockIdx.x, tid = threadIdx.x;
    const int v = vid[u];
    __shared__ float red[8];
    float p = 0.f;
    if (tid < HH) {
        const int i = tid, o = u * HH + i;
        cz[o] = Wz[(size_t)i * (VV + HH) + v] + Wzb[i];
        const float r1 = Wr[(size_t)i * VV + v] + Wrb[i];
        r1s[o] = r1;
        sig0[o] = 1.f / (1.f + expf(-r1));
        ch[o] = Wh[(size_t)i * (VV + HH) + v] + Whb[i];
        float d = Wd12[(size_t)i * (VV + LATD) + v] + Wd12b[i];
        for (int k = 0; k < LATD; ++k)
            d += Wd12[(size_t)i * (VV + LATD) + VV + k] * latent[k];
        p = Ud[i] * fmaxf(d, 0.f);
    }
    p = wred_sum(p);
    if ((tid & 63) == 0) red[tid >> 6] = p;
    __syncthreads();
    if (tid == 0) {
        float s = 0.f;
        for (int w = 0; w < 8; ++w) s += red[w];
        dotd12[u] = s;
    }
}

// ---- WhSig0[u] = Wh_H @ sigma(r1[u]) ----
__global__ __launch_bounds__(512) void k_whsig0(
    const float* __restrict__ Wh, const float* __restrict__ sig0, float* __restrict__ out)
{
    const int u = blockIdx.x, tid = threadIdx.x, wave = tid >> 6, lane = tid & 63;
    __shared__ float sg[HH];
    if (tid < HH) sg[tid] = sig0[u * HH + tid];
    __syncthreads();
    for (int r = wave; r < HH; r += 8) {
        float acc = 0.f;
        for (int k = lane; k < HH; k += 64)
            acc += Wh[(size_t)r * (VV + HH) + VV + k] * sg[k];
        acc = wred_sum(acc);
        if (lane == 0) out[u * HH + r] = acc;
    }
}

// ---- per-step exclusion index + precomputed neighbor-count coefficient ----
__global__ void k_excl(const int* __restrict__ node_ids, const int* __restrict__ next_ids,
                       int* __restrict__ excl, float* __restrict__ ccpre)
{
    const int t = blockIdx.x;
    __shared__ int ex, cnt;
    if (threadIdx.x == 0) { ex = -1; cnt = 0; }
    __syncthreads();
    const int a = node_ids[t], b = next_ids[t];
    for (int tp = threadIdx.x; tp <= t; tp += blockDim.x) {
        if (tp < t && node_ids[tp] == b && next_ids[tp] == a) ex = tp;
        if (tp >= 1 && node_ids[tp] == a) atomicAdd(&cnt, 1);
    }
    __syncthreads();
    if (threadIdx.x == 0) {
        excl[t] = ex;
        ccpre[t] = 256.f - (float)cnt + (ex >= 0 ? 1.f : 0.f);
    }
}

// ---- copy stops/real_labels into d_out; zero the pred_stop region ----
__global__ void k_copy(const int* __restrict__ stops, const int* __restrict__ reall,
                       float* __restrict__ out)
{
    const int i = blockIdx.x * blockDim.x + threadIdx.x;
    if (i < LL) { out[i] = (float)stops[i]; out[LL + i] = 0.f; }
    if (i < NN) out[2 * LL + i] = (float)reall[i];
}

// ---- sequential scan: row-partitioned, block-private state, 2 barriers/step ----
// Block b owns rows [kbeg, kbeg+kcnt). Weight rows in registers. Only nh/sig
// slices (450 floats each) cross blocks per step, via UC publish buffers.
__global__ __launch_bounds__(TSEQ) void k_seq(
    const int* __restrict__ node_ids, const int* __restrict__ excl,
    const float* __restrict__ ccpre,
    const float* __restrict__ Ur, const float* __restrict__ Wz,
    const float* __restrict__ Wh, const float* __restrict__ Wd3,
    const float* __restrict__ Wd3b, const float* __restrict__ Ud,
    const float* __restrict__ Udb,
    const float* __restrict__ cz, const float* __restrict__ r1s,
    const float* __restrict__ ch, const float* __restrict__ WhSig0,
    const float* __restrict__ dotd12,
    float* __restrict__ SmL, float* __restrict__ WzSmL,
    float* __restrict__ Wd3SmL, float* __restrict__ WhRsL,
    float* __restrict__ NewHL, float* __restrict__ WzML, float* __restrict__ WhSvL,
    float* __restrict__ nhPub, float* __restrict__ sigPub,
    float* __restrict__ pred_out, unsigned* __restrict__ bar)
{
    const int tid = threadIdx.x, bid = blockIdx.x;
    const int wave = tid >> 6, lane = tid & 63;
    const int kcnt = 14 + (bid < 2 ? 1 : 0);
    const int kbeg = 14 * bid + (bid < 2 ? bid : 2);

    float* mySm   = SmL    + (size_t)bid * NN * AST;
    float* myWzSm = WzSmL  + (size_t)bid * NN * AST;
    float* myWd3S = Wd3SmL + (size_t)bid * NN * AST;
    float* myWhRs = WhRsL  + (size_t)bid * NN * AST;
    float* myNewH = NewHL  + (size_t)bid * LL * AST;
    float* myWzM  = WzML   + (size_t)bid * LL * AST;
    float* myWhSv = WhSvL  + (size_t)bid * LL * AST;

    __shared__ float nh_full[512];
    __shared__ float sig_full[512];
    __shared__ float nh_mine[KMAX];

    if (tid >= HH) { nh_full[tid] = 0.f; sig_full[tid] = 0.f; }  // zero pad once

    // Preload this block's weight rows into registers (zero-padded)
    float ur_r[2][8], wz_r[2][8], wh_r[2][8], wd3_r[2][8];
    for (int it = 0; it < 2; ++it) {
        const int j = wave + 8 * it;
        const bool vj = j < kcnt;
        const int i = vj ? (kbeg + j) : 0;
        for (int e = 0; e < 8; ++e) {
            const int c = lane + 64 * e;
            const bool v = vj && (c < HH);
            ur_r[it][e]  = v ? Ur[(size_t)i * HH + c] : 0.f;
            wz_r[it][e]  = v ? Wz[(size_t)i * (VV + HH) + VV + c] : 0.f;
            wh_r[it][e]  = v ? Wh[(size_t)i * (VV + HH) + VV + c] : 0.f;
            wd3_r[it][e] = v ? Wd3[(size_t)i * HH + c] : 0.f;
        }
    }
    __syncthreads();

    unsigned ph = 0;
    for (int t = 1; t <= LL; ++t) {
        const int ap  = node_ids[t - 1];
        const int idx = excl[t - 1];
        // ---- A: new_h(t-1) own rows (all-local reads), publish; pred_stop ----
        float ps = 0.f;
        if (tid < kcnt) {
            const int r = kbeg + tid;
            const int o = ap * HH + r;
            const int oa = ap * AST + tid;
            float zarg = myWzSm[oa] + cz[o];
            float whv  = myWhRs[oa] + ch[o];
            float sv   = mySm[oa];
            if (idx >= 0) {
                const int oe = idx * AST + tid;
                zarg -= myWzM[oe]; whv -= myWhSv[oe]; sv -= myNewH[oe];
            }
            whv += ccpre[t - 1] * WhSig0[o];
            const float z = 1.f / (1.f + expf(-zarg));
            const float nh = (1.f - z) * sv + z * tanhf(whv);
            nh_mine[tid] = nh;
            myNewH[(t - 1) * AST + tid] = nh;
            astore(&nhPub[r], nh);
            ps = Ud[HH + r] * fmaxf(myWd3S[oa] + Wd3b[r], 0.f);
        }
        if (tid < 64) {   // wave-0 reduce; one UC add per block (no sync needed)
            ps = wred_sum(ps);
            if (tid == 0) {
                if (bid == 0) ps += dotd12[ap] + Udb[0];
                aadd(&pred_out[t - 1], ps);
            }
        }
        if (t == LL) break;   // last step: no ingestion (is_last masked)
        const int a = node_ids[t];

        gridbar(bar, ++ph);   // B1: all nh(t-1) slices published

        // ---- C: read nh_full; sigma for own rows (publish); fold Wz/Wd3/Sm ----
        if (tid < 225) uc_load2f(nhPub + 2 * tid, nh_full[2 * tid], nh_full[2 * tid + 1]);
        __syncthreads();
        for (int it = 0; it < 2; ++it) {   // sigma first — it gates B2
            const int j = wave + 8 * it;
            float acc = 0.f;
            #pragma unroll
            for (int e = 0; e < 8; ++e) acc += ur_r[it][e] * nh_full[lane + 64 * e];
            acc = wred_sum(acc);
            if (lane == 0 && j < kcnt) {
                const int r = kbeg + j;
                astore(&sigPub[r], 1.f / (1.f + expf(-(acc + r1s[a * HH + r]))));
            }
        }
        for (int it = 0; it < 2; ++it) {
            const int j = wave + 8 * it;
            float az = 0.f, ad = 0.f;
            #pragma unroll
            for (int e = 0; e < 8; ++e) {
                const float nv = nh_full[lane + 64 * e];
                az += wz_r[it][e] * nv;
                ad += wd3_r[it][e] * nv;
            }
            az = wred_sum(az); ad = wred_sum(ad);
            if (lane == 0 && j < kcnt) {
                myWzM[(t - 1) * AST + j] = az;
                myWzSm[a * AST + j] += az;
                myWd3S[a * AST + j] += ad;
            }
        }
        if (tid < kcnt) mySm[a * AST + tid] += nh_mine[tid];

        gridbar(bar, ++ph);   // B2: all sigma slices published

        // ---- D: read sig_full; fold Wh rows ----
        if (tid < 225) uc_load2f(sigPub + 2 * tid, sig_full[2 * tid], sig_full[2 * tid + 1]);
        __syncthreads();
        for (int it = 0; it < 2; ++it) {
            const int j = wave + 8 * it;
            float acc = 0.f;
            #pragma unroll
            for (int e = 0; e < 8; ++e) acc += wh_r[it][e] * sig_full[lane + 64 * e];
            acc = wred_sum(acc);
            if (lane == 0 && j < kcnt) {
                myWhSv[(t - 1) * AST + j] = acc;
                myWhRs[a * AST + j] += acc;
            }
        }
        __syncthreads();   // next A reads this iter's local folds
    }
}

// ---- labels: root (q=0, outer relu, no softmax) + 255 label steps (softmax) ----
__global__ __launch_bounds__(512) void k_label(
    const float* __restrict__ latent, const int* __restrict__ lsteps,
    const float* __restrict__ NewHL,
    const float* __restrict__ Wl, const float* __restrict__ Wlb,
    const float* __restrict__ Ul, const float* __restrict__ Ulb,
    float* __restrict__ out)
{
    const int q = blockIdx.x, tid = threadIdx.x, wave = tid >> 6, lane = tid & 63;
    __shared__ float inp[LATD + HH];
    __shared__ float t2[HH];
    __shared__ float lg[VV];
    __shared__ float red[8];
    if (tid < LATD) inp[tid] = latent[tid];
    if (q == 0) {
        if (tid < HH) inp[LATD + tid] = 0.f;
    } else {
        const int t = lsteps[q - 1];
        if (tid < HH) {
            const int b = (tid < 30) ? (tid / 15) : (2 + (tid - 30) / 14);
            const int j = (tid < 30) ? (tid % 15) : ((tid - 30) % 14);
            inp[LATD + tid] = NewHL[((size_t)b * LL + t) * AST + j];
        }
    }
    __syncthreads();
    for (int r = wave; r < HH; r += 8) {
        float acc = 0.f;
        for (int k = lane; k < LATD + HH; k += 64)
            acc += Wl[(size_t)r * (LATD + HH) + k] * inp[k];
        acc = wred_sum(acc);
        if (lane == 0) {
            const float v = acc + Wlb[r];
            t2[r] = (q == 0) ? v : fmaxf(v, 0.f);   // root: no inner relu
        }
    }
    __syncthreads();
    for (int r = wave; r < VV; r += 8) {
        float acc = 0.f;
        for (int k = lane; k < HH; k += 64) acc += Ul[(size_t)r * HH + k] * t2[k];
        acc = wred_sum(acc);
        if (lane == 0) lg[r] = acc + Ulb[r];
    }
    __syncthreads();
    float* outrow = out + 2 * LL + NN + (size_t)q * VV;
    if (q == 0) {   // root: relu, no softmax
        for (int i = tid; i < VV; i += 512) outrow[i] = fmaxf(lg[i], 0.f);
        return;
    }
    float mx = -1e30f;
    for (int i = tid; i < VV; i += 512) mx = fmaxf(mx, lg[i]);
    for (int off = 32; off; off >>= 1) mx = fmaxf(mx, __shfl_down(mx, off, 64));
    if (lane == 0) red[wave] = mx;
    __syncthreads();
    if (tid == 0) {
        float m = red[0];
        for (int w = 1; w < 8; ++w) m = fmaxf(m, red[w]);
        red[0] = m;
    }
    __syncthreads();
    const float M = red[0];
    float sum = 0.f;
    for (int i = tid; i < VV; i += 512) { const float e = expf(lg[i] - M); lg[i] = e; sum += e; }
    __syncthreads();
    sum = wred_sum(sum);
    if (lane == 0) red[wave] = sum;
    __syncthreads();
    if (tid == 0) {
        float s = 0.f;
        for (int w = 0; w < 8; ++w) s += red[w];
        red[0] = s;
    }
    __syncthreads();
    const float S = red[0];
    for (int i = tid; i < VV; i += 512) outrow[i] = lg[i] / S;
}

extern "C" void kernel_launch(void* const* d_in, const int* in_sizes, int n_in,
                              void* d_out, int out_size, void* d_ws, size_t ws_size,
                              hipStream_t stream)
{
    const float* latent = (const float*)d_in[0];
    const float* nodef  = (const float*)d_in[1];
    const int* node_ids = (const int*)d_in[2];
    const int* next_ids = (const int*)d_in[3];
    const int* stops    = (const int*)d_in[4];
    const int* lsteps   = (const int*)d_in[5];
    const int* reall    = (const int*)d_in[6];
    const float* Wz   = (const float*)d_in[7];
    const float* Wzb  = (const float*)d_in[8];
    const float* Urw  = (const float*)d_in[9];
    const float* Wr   = (const float*)d_in[10];
    const float* Wrb  = (const float*)d_in[11];
    const float* Wh   = (const float*)d_in[12];
    const float* Whb  = (const float*)d_in[13];
    const float* Wd12 = (const float*)d_in[14];
    const float* Wd12b= (const float*)d_in[15];
    const float* Wd3  = (const float*)d_in[16];
    const float* Wd3b = (const float*)d_in[17];
    const float* Ud   = (const float*)d_in[18];
    const float* Udb  = (const float*)d_in[19];
    const float* Wl   = (const float*)d_in[20];
    const float* Wlb  = (const float*)d_in[21];
    const float* Ul   = (const float*)d_in[22];
    const float* Ulb  = (const float*)d_in[23];
    (void)in_sizes; (void)n_in; (void)out_size; (void)ws_size;
    float* out = (float*)d_out;
    float* W = (float*)d_ws;

    size_t o = 0;
    float* SmL    = W + o; o += (size_t)GSEQ * NN * AST;
    float* WzSmL  = W + o; o += (size_t)GSEQ * NN * AST;
    float* Wd3SmL = W + o; o += (size_t)GSEQ * NN * AST;
    float* WhRsL  = W + o; o += (size_t)GSEQ * NN * AST;
    unsigned* bar = (unsigned*)(W + o); o += GSEQ * SLOTPAD;
    const size_t zero_floats = o;           // everything above must start at 0
    int*   vid    = (int*)(W + o); o += NN;
    int*   excl   = (int*)(W + o); o += LL + 1;
    float* ccpre  = W + o; o += LL + 1;
    float* cz     = W + o; o += NN * HH;
    float* r1s    = W + o; o += NN * HH;
    float* sig0   = W + o; o += NN * HH;
    float* ch     = W + o; o += NN * HH;
    float* WhSig0 = W + o; o += NN * HH;
    float* dotd12 = W + o; o += NN;
    float* NewHL  = W + o; o += (size_t)GSEQ * LL * AST;
    float* WzML   = W + o; o += (size_t)GSEQ * LL * AST;
    float* WhSvL  = W + o; o += (size_t)GSEQ * LL * AST;
    float* nhPub  = W + o; o += 512;
    float* sigPub = W + o; o += 512;

    hipMemsetAsync(W, 0, zero_floats * sizeof(float), stream);
    k_vid   <<<NN, 256, 0, stream>>>(nodef, vid);
    k_consts<<<NN, 512, 0, stream>>>(vid, latent, Wz, Wzb, Wr, Wrb, Wh, Whb,
                                     Wd12, Wd12b, Ud, cz, r1s, sig0, ch, dotd12);
    k_whsig0<<<NN, 512, 0, stream>>>(Wh, sig0, WhSig0);
    k_excl  <<<LL, 256, 0, stream>>>(node_ids, next_ids, excl, ccpre);
    k_copy  <<<2, 256, 0, stream>>>(stops, reall, out);
    k_seq   <<<GSEQ, TSEQ, 0, stream>>>(node_ids, excl, ccpre, Urw, Wz, Wh, Wd3, Wd3b,
                                        Ud, Udb, cz, r1s, ch, WhSig0, dotd12,
                                        SmL, WzSmL, Wd3SmL, WhRsL,
                                        NewHL, WzML, WhSvL, nhPub, sigPub,
                                        out + LL, bar);
    k_label <<<NN, 512, 0, stream>>>(latent, lsteps, NewHL, Wl, Wlb, Ul, Ulb, out);
}

// Round 5
// 3340.391 us; speedup vs baseline: 3.3092x; 1.2136x over previous
//
#include <hip/hip_runtime.h>
#include <math.h>

// Problem constants (fixed by setup_inputs)
#define NN   256   // nodes
#define HH   450   // hidden
#define LATD 56    // latent
#define VV   780   // vocab
#define LL   511   // path length (2N-1)
#define GSEQ 32    // persistent blocks
#define TSEQ 512   // threads per persistent block
#define KMAX 15    // max rows per block (450 = 15+15+14*30)
#define AST  16    // accumulator row stride (pad 15 -> 16)

__device__ __forceinline__ float wred_sum(float v) {
    for (int off = 32; off; off >>= 1) v += __shfl_down(v, off, 64);
    return v;
}

// ---- agent-scope relaxed atomics (UC, coherent at device level) ----
__device__ __forceinline__ float aload(const float* p) {
    return __hip_atomic_load(p, __ATOMIC_RELAXED, __HIP_MEMORY_SCOPE_AGENT);
}
__device__ __forceinline__ void aadd(float* p, float v) {
    (void)__hip_atomic_fetch_add(p, v, __ATOMIC_RELAXED, __HIP_MEMORY_SCOPE_AGENT);
}

// ---- find vocab id of each node's one-hot feature ----
__global__ void k_vid(const float* __restrict__ nf, int* __restrict__ vid) {
    const int u = blockIdx.x;
    for (int v = threadIdx.x; v < VV; v += blockDim.x)
        if (nf[(size_t)u * VV + v] > 0.5f) vid[u] = v;
}

// ---- per-node constants: cz, r1, sigma(r1), ch, and Ud . relu(d12) scalar ----
__global__ __launch_bounds__(512) void k_consts(
    const int* __restrict__ vid, const float* __restrict__ latent,
    const float* __restrict__ Wz, const float* __restrict__ Wzb,
    const float* __restrict__ Wr, const float* __restrict__ Wrb,
    const float* __restrict__ Wh, const float* __restrict__ Whb,
    const float* __restrict__ Wd12, const float* __restrict__ Wd12b,
    const float* __restrict__ Ud,
    float* __restrict__ cz, float* __restrict__ r1s, float* __restrict__ sig0,
    float* __restrict__ ch, float* __restrict__ dotd12)
{
    const int u = blockIdx.x, tid = threadIdx.x;
    const int v = vid[u];
    __shared__ float red[8];
    float p = 0.f;
    if (tid < HH) {
        const int i = tid, o = u * HH + i;
        cz[o] = Wz[(size_t)i * (VV + HH) + v] + Wzb[i];
        const float r1 = Wr[(size_t)i * VV + v] + Wrb[i];
        r1s[o] = r1;
        sig0[o] = 1.f / (1.f + expf(-r1));
        ch[o] = Wh[(size_t)i * (VV + HH) + v] + Whb[i];
        float d = Wd12[(size_t)i * (VV + LATD) + v] + Wd12b[i];
        for (int k = 0; k < LATD; ++k)
            d += Wd12[(size_t)i * (VV + LATD) + VV + k] * latent[k];
        p = Ud[i] * fmaxf(d, 0.f);
    }
    p = wred_sum(p);
    if ((tid & 63) == 0) red[tid >> 6] = p;
    __syncthreads();
    if (tid == 0) {
        float s = 0.f;
        for (int w = 0; w < 8; ++w) s += red[w];
        dotd12[u] = s;
    }
}

// ---- WhSig0[u] = Wh_H @ sigma(r1[u]) ----
__global__ __launch_bounds__(512) void k_whsig0(
    const float* __restrict__ Wh, const float* __restrict__ sig0, float* __restrict__ out)
{
    const int u = blockIdx.x, tid = threadIdx.x, wave = tid >> 6, lane = tid & 63;
    __shared__ float sg[HH];
    if (tid < HH) sg[tid] = sig0[u * HH + tid];
    __syncthreads();
    for (int r = wave; r < HH; r += 8) {
        float acc = 0.f;
        for (int k = lane; k < HH; k += 64)
            acc += Wh[(size_t)r * (VV + HH) + VV + k] * sg[k];
        acc = wred_sum(acc);
        if (lane == 0) out[u * HH + r] = acc;
    }
}

// ---- per-step exclusion index + precomputed neighbor-count coefficient ----
__global__ void k_excl(const int* __restrict__ node_ids, const int* __restrict__ next_ids,
                       int* __restrict__ excl, float* __restrict__ ccpre)
{
    const int t = blockIdx.x;
    __shared__ int ex, cnt;
    if (threadIdx.x == 0) { ex = -1; cnt = 0; }
    __syncthreads();
    const int a = node_ids[t], b = next_ids[t];
    for (int tp = threadIdx.x; tp <= t; tp += blockDim.x) {
        if (tp < t && node_ids[tp] == b && next_ids[tp] == a) ex = tp;
        if (tp >= 1 && node_ids[tp] == a) atomicAdd(&cnt, 1);
    }
    __syncthreads();
    if (threadIdx.x == 0) {
        excl[t] = ex;
        ccpre[t] = 256.f - (float)cnt + (ex >= 0 ? 1.f : 0.f);
    }
}

// ---- copy stops/real_labels into d_out; zero the pred_stop region ----
__global__ void k_copy(const int* __restrict__ stops, const int* __restrict__ reall,
                       float* __restrict__ out)
{
    const int i = blockIdx.x * blockDim.x + threadIdx.x;
    if (i < LL) { out[i] = (float)stops[i]; out[LL + i] = 0.f; }
    if (i < NN) out[2 * LL + i] = (float)reall[i];
}

// ---- sequential scan: ONE sync chain per step ----
// Block b owns rows R_b = [kbeg, kbeg+kcnt). First-layer matvecs (Ur, Wz_H,
// Wd3) are COLUMN-partitioned: right after nh_mine (local), each thread r<450
// fans its partial into monotone accumulation buffers (parity double-buffered,
// consumers diff against per-thread prev — no zeroing, no races: a block can
// be at most 1 step ahead because cnt gates every step). One counter poll is
// the only sync. sigma is then computed redundantly for all rows; the Wh
// matvec stays row-partitioned with register-resident rows.
__global__ __launch_bounds__(TSEQ) void k_seq(
    const int* __restrict__ node_ids, const int* __restrict__ excl,
    const float* __restrict__ ccpre,
    const float* __restrict__ Ur, const float* __restrict__ Wz,
    const float* __restrict__ Wh, const float* __restrict__ Wd3,
    const float* __restrict__ Wd3b, const float* __restrict__ Ud,
    const float* __restrict__ Udb,
    const float* __restrict__ cz, const float* __restrict__ r1s,
    const float* __restrict__ ch, const float* __restrict__ WhSig0,
    const float* __restrict__ dotd12,
    float* __restrict__ SmL, float* __restrict__ WzSmL,
    float* __restrict__ Wd3SmL, float* __restrict__ WhRsL,
    float* __restrict__ NewHL, float* __restrict__ WzML, float* __restrict__ WhSvL,
    float* __restrict__ bufUr, float* __restrict__ bufWz, float* __restrict__ bufWd3,
    unsigned* __restrict__ cnt,
    float* __restrict__ pred_out)
{
    const int tid = threadIdx.x, bid = blockIdx.x;
    const int wave = tid >> 6, lane = tid & 63;
    const int kcnt = 14 + (bid < 2 ? 1 : 0);
    const int kbeg = 14 * bid + (bid < 2 ? bid : 2);

    float* mySm   = SmL    + (size_t)bid * NN * AST;
    float* myWzSm = WzSmL  + (size_t)bid * NN * AST;
    float* myWd3S = Wd3SmL + (size_t)bid * NN * AST;
    float* myWhRs = WhRsL  + (size_t)bid * NN * AST;
    float* myNewH = NewHL  + (size_t)bid * LL * AST;
    float* myWzM  = WzML   + (size_t)bid * LL * AST;
    float* myWhSv = WhSvL  + (size_t)bid * LL * AST;

    __shared__ float nh_s[KMAX];
    __shared__ float sig_full[512];

    // Column slices of Ur / Wz_H / Wd3: thread r holds row r's R_b columns
    float ur_c[KMAX], wz_c[KMAX], wd3_c[KMAX];
    for (int j = 0; j < KMAX; ++j) {
        const bool v = (tid < HH) && (j < kcnt);
        ur_c[j]  = v ? Ur[(size_t)tid * HH + kbeg + j] : 0.f;
        wz_c[j]  = v ? Wz[(size_t)tid * (VV + HH) + VV + kbeg + j] : 0.f;
        wd3_c[j] = v ? Wd3[(size_t)tid * HH + kbeg + j] : 0.f;
    }
    // Row slice of Wh_H (for the second matvec fold)
    float wh_r[2][8];
    for (int it = 0; it < 2; ++it) {
        const int j = wave + 8 * it;
        const bool vj = j < kcnt;
        const int i = vj ? (kbeg + j) : 0;
        for (int e = 0; e < 8; ++e) {
            const int c = lane + 64 * e;
            wh_r[it][e] = (vj && c < HH) ? Wh[(size_t)i * (VV + HH) + VV + c] : 0.f;
        }
    }
    if (tid >= HH) sig_full[tid] = 0.f;   // zero pad once

    float prevUr[2]  = {0.f, 0.f};
    float prevWz[2]  = {0.f, 0.f};
    float prevWd3[2] = {0.f, 0.f};
    __syncthreads();

    for (int t = 1; t <= LL; ++t) {
        const int ap  = node_ids[t - 1];
        const int idx = excl[t - 1];
        // ---- A: new_h(t-1) own rows (all-local reads) ----
        float nh = 0.f;
        if (tid < kcnt) {
            const int r = kbeg + tid;
            const int o = ap * HH + r;
            const int oa = ap * AST + tid;
            float zarg = myWzSm[oa] + cz[o];
            float whv  = myWhRs[oa] + ch[o];
            float sv   = mySm[oa];
            if (idx >= 0) {
                const int oe = idx * AST + tid;
                zarg -= myWzM[oe]; whv -= myWhSv[oe]; sv -= myNewH[oe];
            }
            whv += ccpre[t - 1] * WhSig0[o];
            const float z = 1.f / (1.f + expf(-zarg));
            nh = (1.f - z) * sv + z * tanhf(whv);
            nh_s[tid] = nh;
            myNewH[(t - 1) * AST + tid] = nh;
        }
        // pred_stop(t-1): own rows live in wave 0 (kcnt <= 15); fire-and-forget
        if (wave == 0) {
            float ps = 0.f;
            if (tid < kcnt) {
                const int r = kbeg + tid;
                ps = Ud[HH + r] * fmaxf(myWd3S[ap * AST + tid] + Wd3b[r], 0.f);
            }
            ps = wred_sum(ps);
            if (lane == 0) {
                if (bid == 0) ps += dotd12[ap] + Udb[0];
                aadd(&pred_out[t - 1], ps);
            }
        }
        if (t == LL) break;   // last step: no ingestion (is_last masked)
        const int a = node_ids[t];
        __syncthreads();       // nh_s visible

        // ---- fan-out: column partials into monotone buffers ----
        const int p = t & 1;
        if (tid < HH) {
            float au = 0.f, az = 0.f, ad = 0.f;
            for (int j = 0; j < kcnt; ++j) {
                const float m = nh_s[j];
                au += ur_c[j]  * m;
                az += wz_c[j]  * m;
                ad += wd3_c[j] * m;
            }
            aadd(&bufUr[p * 512 + tid], au);
            aadd(&bufWz[p * 512 + tid], az);
            aadd(&bufWd3[p * 512 + tid], ad);
        }
        if (tid < kcnt) mySm[a * AST + tid] += nh;   // local fold (hides drain)
        asm volatile("s_waitcnt vmcnt(0)" ::: "memory");   // my adds landed
        __syncthreads();
        if (tid == 0) {
            (void)__hip_atomic_fetch_add(cnt, 1u, __ATOMIC_RELAXED,
                                         __HIP_MEMORY_SCOPE_AGENT);
            while (__hip_atomic_load(cnt, __ATOMIC_RELAXED,
                                     __HIP_MEMORY_SCOPE_AGENT) < 32u * (unsigned)t)
                __builtin_amdgcn_s_sleep(1);
        }
        __syncthreads();   // cnt == 32t: all blocks' adds for step t landed

        // ---- gather + diff + sigma (all rows, redundant) ----
        if (tid < HH) {
            const float cu = aload(&bufUr[p * 512 + tid]);
            const float urm = cu - prevUr[p]; prevUr[p] = cu;
            sig_full[tid] = 1.f / (1.f + expf(-(urm + r1s[a * HH + tid])));
        }
        if (tid < kcnt) {
            const float cw = aload(&bufWz[p * 512 + kbeg + tid]);
            const float wzm = cw - prevWz[p]; prevWz[p] = cw;
            myWzM[(t - 1) * AST + tid] = wzm;
            myWzSm[a * AST + tid] += wzm;
            const float cd = aload(&bufWd3[p * 512 + kbeg + tid]);
            myWd3S[a * AST + tid] += cd - prevWd3[p]; prevWd3[p] = cd;
        }
        __syncthreads();   // sig_full ready

        // ---- Wh fold: own rows x full sigma (register matvec) ----
        for (int it = 0; it < 2; ++it) {
            const int j = wave + 8 * it;
            float acc = 0.f;
            #pragma unroll
            for (int e = 0; e < 8; ++e) acc += wh_r[it][e] * sig_full[lane + 64 * e];
            acc = wred_sum(acc);
            if (lane == 0 && j < kcnt) {
                myWhSv[(t - 1) * AST + j] = acc;
                myWhRs[a * AST + j] += acc;
            }
        }
        __syncthreads();   // folds complete before next A reads them
    }
}

// ---- labels: root (q=0, outer relu, no softmax) + 255 label steps (softmax) ----
__global__ __launch_bounds__(512) void k_label(
    const float* __restrict__ latent, const int* __restrict__ lsteps,
    const float* __restrict__ NewHL,
    const float* __restrict__ Wl, const float* __restrict__ Wlb,
    const float* __restrict__ Ul, const float* __restrict__ Ulb,
    float* __restrict__ out)
{
    const int q = blockIdx.x, tid = threadIdx.x, wave = tid >> 6, lane = tid & 63;
    __shared__ float inp[LATD + HH];
    __shared__ float t2[HH];
    __shared__ float lg[VV];
    __shared__ float red[8];
    if (tid < LATD) inp[tid] = latent[tid];
    if (q == 0) {
        if (tid < HH) inp[LATD + tid] = 0.f;
    } else {
        const int t = lsteps[q - 1];
        if (tid < HH) {
            const int b = (tid < 30) ? (tid / 15) : (2 + (tid - 30) / 14);
            const int j = (tid < 30) ? (tid % 15) : ((tid - 30) % 14);
            inp[LATD + tid] = NewHL[((size_t)b * LL + t) * AST + j];
        }
    }
    __syncthreads();
    for (int r = wave; r < HH; r += 8) {
        float acc = 0.f;
        for (int k = lane; k < LATD + HH; k += 64)
            acc += Wl[(size_t)r * (LATD + HH) + k] * inp[k];
        acc = wred_sum(acc);
        if (lane == 0) {
            const float v = acc + Wlb[r];
            t2[r] = (q == 0) ? v : fmaxf(v, 0.f);   // root: no inner relu
        }
    }
    __syncthreads();
    for (int r = wave; r < VV; r += 8) {
        float acc = 0.f;
        for (int k = lane; k < HH; k += 64) acc += Ul[(size_t)r * HH + k] * t2[k];
        acc = wred_sum(acc);
        if (lane == 0) lg[r] = acc + Ulb[r];
    }
    __syncthreads();
    float* outrow = out + 2 * LL + NN + (size_t)q * VV;
    if (q == 0) {   // root: relu, no softmax
        for (int i = tid; i < VV; i += 512) outrow[i] = fmaxf(lg[i], 0.f);
        return;
    }
    float mx = -1e30f;
    for (int i = tid; i < VV; i += 512) mx = fmaxf(mx, lg[i]);
    for (int off = 32; off; off >>= 1) mx = fmaxf(mx, __shfl_down(mx, off, 64));
    if (lane == 0) red[wave] = mx;
    __syncthreads();
    if (tid == 0) {
        float m = red[0];
        for (int w = 1; w < 8; ++w) m = fmaxf(m, red[w]);
        red[0] = m;
    }
    __syncthreads();
    const float M = red[0];
    float sum = 0.f;
    for (int i = tid; i < VV; i += 512) { const float e = expf(lg[i] - M); lg[i] = e; sum += e; }
    __syncthreads();
    sum = wred_sum(sum);
    if (lane == 0) red[wave] = sum;
    __syncthreads();
    if (tid == 0) {
        float s = 0.f;
        for (int w = 0; w < 8; ++w) s += red[w];
        red[0] = s;
    }
    __syncthreads();
    const float S = red[0];
    for (int i = tid; i < VV; i += 512) outrow[i] = lg[i] / S;
}

extern "C" void kernel_launch(void* const* d_in, const int* in_sizes, int n_in,
                              void* d_out, int out_size, void* d_ws, size_t ws_size,
                              hipStream_t stream)
{
    const float* latent = (const float*)d_in[0];
    const float* nodef  = (const float*)d_in[1];
    const int* node_ids = (const int*)d_in[2];
    const int* next_ids = (const int*)d_in[3];
    const int* stops    = (const int*)d_in[4];
    const int* lsteps   = (const int*)d_in[5];
    const int* reall    = (const int*)d_in[6];
    const float* Wz   = (const float*)d_in[7];
    const float* Wzb  = (const float*)d_in[8];
    const float* Urw  = (const float*)d_in[9];
    const float* Wr   = (const float*)d_in[10];
    const float* Wrb  = (const float*)d_in[11];
    const float* Wh   = (const float*)d_in[12];
    const float* Whb  = (const float*)d_in[13];
    const float* Wd12 = (const float*)d_in[14];
    const float* Wd12b= (const float*)d_in[15];
    const float* Wd3  = (const float*)d_in[16];
    const float* Wd3b = (const float*)d_in[17];
    const float* Ud   = (const float*)d_in[18];
    const float* Udb  = (const float*)d_in[19];
    const float* Wl   = (const float*)d_in[20];
    const float* Wlb  = (const float*)d_in[21];
    const float* Ul   = (const float*)d_in[22];
    const float* Ulb  = (const float*)d_in[23];
    (void)in_sizes; (void)n_in; (void)out_size; (void)ws_size;
    float* out = (float*)d_out;
    float* W = (float*)d_ws;

    size_t o = 0;
    float* SmL    = W + o; o += (size_t)GSEQ * NN * AST;
    float* WzSmL  = W + o; o += (size_t)GSEQ * NN * AST;
    float* Wd3SmL = W + o; o += (size_t)GSEQ * NN * AST;
    float* WhRsL  = W + o; o += (size_t)GSEQ * NN * AST;
    float* bufUr  = W + o; o += 2 * 512;
    float* bufWz  = W + o; o += 2 * 512;
    float* bufWd3 = W + o; o += 2 * 512;
    unsigned* cnt = (unsigned*)(W + o); o += 16;
    const size_t zero_floats = o;           // everything above must start at 0
    int*   vid    = (int*)(W + o); o += NN;
    int*   excl   = (int*)(W + o); o += LL + 1;
    float* ccpre  = W + o; o += LL + 1;
    float* cz     = W + o; o += NN * HH;
    float* r1s    = W + o; o += NN * HH;
    float* sig0   = W + o; o += NN * HH;
    float* ch     = W + o; o += NN * HH;
    float* WhSig0 = W + o; o += NN * HH;
    float* dotd12 = W + o; o += NN;
    float* NewHL  = W + o; o += (size_t)GSEQ * LL * AST;
    float* WzML   = W + o; o += (size_t)GSEQ * LL * AST;
    float* WhSvL  = W + o; o += (size_t)GSEQ * LL * AST;

    hipMemsetAsync(W, 0, zero_floats * sizeof(float), stream);
    k_vid   <<<NN, 256, 0, stream>>>(nodef, vid);
    k_consts<<<NN, 512, 0, stream>>>(vid, latent, Wz, Wzb, Wr, Wrb, Wh, Whb,
                                     Wd12, Wd12b, Ud, cz, r1s, sig0, ch, dotd12);
    k_whsig0<<<NN, 512, 0, stream>>>(Wh, sig0, WhSig0);
    k_excl  <<<LL, 256, 0, stream>>>(node_ids, next_ids, excl, ccpre);
    k_copy  <<<2, 256, 0, stream>>>(stops, reall, out);
    k_seq   <<<GSEQ, TSEQ, 0, stream>>>(node_ids, excl, ccpre, Urw, Wz, Wh, Wd3, Wd3b,
                                        Ud, Udb, cz, r1s, ch, WhSig0, dotd12,
                                        SmL, WzSmL, Wd3SmL, WhRsL,
                                        NewHL, WzML, WhSvL,
                                        bufUr, bufWz, bufWd3, cnt,
                                        out + LL);
    k_label <<<NN, 512, 0, stream>>>(latent, lsteps, NewHL, Wl, Wlb, Ul, Ulb, out);
}